// Round 20
// baseline (724.259 us; speedup 1.0000x reference)
//
#include <hip/hip_runtime.h>
#include <hip/hip_bf16.h>

#define E_ 8
#define B_ 8
#define S_ 2048
#define D_ 512
#define R_ 128
#define M_TOT (B_ * S_)   // 16384

typedef __attribute__((ext_vector_type(8))) short bf16x8;
typedef __attribute__((ext_vector_type(4))) float f32x4;
typedef __attribute__((ext_vector_type(4))) short s16x4;

__device__ __forceinline__ void gload_lds16(void* lds, const void* g) {
  __builtin_amdgcn_global_load_lds(
      (const __attribute__((address_space(1))) void*)g,
      (__attribute__((address_space(3))) void*)lds, 16, 0, 0);
}

// ---------------------------------------------------------------------------
// Prep kernel: W only (x conversion folded into the GEMM's A-staging).
//   [0,32)      rotation: W[e] cols 0..128 (one-shot slab, R13-proven)
//   [32,2080)   W tail cols 129..511 = bf16(proj_w)
// ---------------------------------------------------------------------------
#define ROT_B 32
#define WT_B 2048
__global__ __launch_bounds__(256) void prep_w(
    const float* __restrict__ theta, const float* __restrict__ pw,
    __hip_bfloat16* __restrict__ Wb) {
  int blk = blockIdx.x;
  int t = threadIdx.x;
  if (blk < ROT_B) {
    __shared__ float cs[R_], ss[R_];
    __shared__ float Pch[128][130];
    __shared__ __hip_bfloat16 Wch[128][130];
    int e = blk >> 2;
    int r0 = (blk & 3) * 128;
    if (t < R_) {
      float a = tanhf(theta[e * R_ + t]) * 0.1f;
      cs[t] = cosf(a);
      ss[t] = sinf(a);
    }
    const float* Pe = pw + (size_t)e * D_ * D_;
    __hip_bfloat16* We = Wb + (size_t)e * D_ * D_;
#pragma unroll 8
    for (int it = 0; it < 64; ++it) {
      int row = it * 2 + (t >> 7);
      int col = t & 127;
      Pch[row][col] = Pe[(size_t)(r0 + row) * D_ + col];
    }
    if (t < 128) Pch[t][128] = Pe[(size_t)(r0 + t) * D_ + 128];
    __syncthreads();
    if (t < 128) {
      float u = Pch[t][0];
#pragma unroll 16
      for (int k = 0; k < R_; ++k) {
        float pj = Pch[t][k + 1];
        Wch[t][k + 1] = __float2bfloat16(cs[k] * pj - ss[k] * u);
        u = cs[k] * u + ss[k] * pj;
      }
      Wch[t][0] = __float2bfloat16(u);
    }
    __syncthreads();
#pragma unroll 8
    for (int it = 0; it < 64; ++it) {
      int row = it * 2 + (t >> 7);
      int col = t & 127;
      We[(size_t)(r0 + row) * D_ + col] = Wch[row][col];
    }
    if (t < 128) We[(size_t)(r0 + t) * D_ + 128] = Wch[t][128];
  } else {
    int g = (blk - ROT_B) * 256 + t;
    int gidx = g & 127;
    if (gidx < 32) return;
    float4 v = ((const float4*)pw)[g];
    union { short4 s; __hip_bfloat16 h[4]; } u;
    u.h[0] = __float2bfloat16(v.x);
    u.h[1] = __float2bfloat16(v.y);
    u.h[2] = __float2bfloat16(v.z);
    u.h[3] = __float2bfloat16(v.w);
    if (gidx > 32) {
      ((short4*)Wb)[g] = u.s;
    } else {
      Wb[(size_t)g * 4 + 1] = u.h[1];
      Wb[(size_t)g * 4 + 2] = u.h[2];
      Wb[(size_t)g * 4 + 3] = u.h[3];
    }
  }
}

// ---------------------------------------------------------------------------
// GEMM: out[e] = x @ Wb[e]^T, A read directly as f32 + cvt in-kernel.
// R19 counters (first visible GEMM profile): FETCH 174MB, 2.8 TB/s, 18%
// MfmaUtil -> fetch-bound because A-loads were NONTEMPORAL, defeating the
// XCD swizzle's designed 32x A-panel L2 reuse. R20: plain (cached) A loads;
// nt retained only on the write-once out stores. Also launch_bounds(256,3):
// VGPR 124 + LDS 48KB allow 3 blocks/CU.
// Schedule per iter t (race-fenced per rule #18: SB0 after every barrier):
//   [vmcnt(2); lgkm; SB0; s_barrier; SB0;
//    issue A(t+2) loads; SB0; MFMA(t);
//    lgkm; SB0; s_barrier; SB0; BLOAD(t+2); AWRITE(t+2)]
// ---------------------------------------------------------------------------
__global__ __launch_bounds__(256, 3) void gemm_xw(
    const float* __restrict__ Xf,            // [M_TOT][512] f32
    const __hip_bfloat16* __restrict__ Wb,   // [E][512][512] rows=o, cols=d
    float* __restrict__ out)                 // [E][M_TOT][512]
{
  constexpr int BM = 256, BN = 128, BK = 32;
  constexpr int KD = D_, ND = D_;
  constexpr int NT = KD / BK;  // 16
  __shared__ __align__(16) char smem[49152];
  __hip_bfloat16 (*As)[BM * BK] =
      (__hip_bfloat16 (*)[BM * BK]) & smem[0];         // 2 x 16 KB
  __hip_bfloat16 (*Bs)[BN * BK] =
      (__hip_bfloat16 (*)[BN * BK]) & smem[32768];     // 2 x 8 KB
  float* Lep = (float*)&smem[0];                       // epilogue: 2x32x132 f32

  int bx = blockIdx.x;            // 2048 blocks
  int xcd = bx & 7, c = bx >> 3;  // chunk c in [0,256) per XCD
  int e = c >> 5;                 // 0..7  (e-major within XCD)
  int msub = (c >> 2) & 7;        // 0..7
  int nt = c & 3;                 // 0..3
  int mt = xcd * 8 + msub;        // 0..63

  int tid = threadIdx.x;
  int wave = tid >> 6, lane = tid & 63;
  int lr = lane & 15, lk = lane >> 4;
  int wm = wave >> 1, wn = wave & 1;   // 2x2 waves; wave-tile 128x64

  const float* Ag = Xf + (size_t)(mt * BM) * KD;
  const __hip_bfloat16* Bg = Wb + ((size_t)e * ND + (size_t)nt * BN) * KD;

  int srow = lane >> 2;
  int scol = (lane & 3) * 8;
  int arow = lane >> 3;        // A: 8 rows per instr
  int acol = (lane & 7) * 4;   // f32 elems within row

  int aoff = (wm * 128 + lr) * BK + lk * 8;
  int boff = (wn * 64 + lr) * BK + lk * 8;

  f32x4 acc[8][4];
#pragma unroll
  for (int i = 0; i < 8; ++i)
#pragma unroll
    for (int j = 0; j < 4; ++j) acc[i][j] = (f32x4){0.f, 0.f, 0.f, 0.f};

#define SB0 __builtin_amdgcn_sched_barrier(0)

#define ALOAD(ar, t)                                                         \
  {                                                                          \
    _Pragma("unroll") for (int j = 0; j < 8; ++j) {                          \
      int row = wave * 64 + j * 8 + arow;                                    \
      ar[j] = *(const f32x4*)(Ag + (size_t)row * KD + (t) * BK + acol);      \
    }                                                                        \
  }
#define AWRITE(ar, buf)                                                      \
  {                                                                          \
    _Pragma("unroll") for (int j = 0; j < 8; ++j) {                          \
      int row = wave * 64 + j * 8 + arow;                                    \
      union { s16x4 s; __hip_bfloat16 h[4]; } u;                             \
      u.h[0] = __float2bfloat16(ar[j].x);                                    \
      u.h[1] = __float2bfloat16(ar[j].y);                                    \
      u.h[2] = __float2bfloat16(ar[j].z);                                    \
      u.h[3] = __float2bfloat16(ar[j].w);                                    \
      *(s16x4*)&As[buf][row * BK + acol] = u.s;                              \
    }                                                                        \
  }
#define BLOAD(buf, t)                                                        \
  {                                                                          \
    _Pragma("unroll") for (int g = 0; g < 2; ++g) {                          \
      int rb = wave * 32 + g * 16;                                           \
      gload_lds16(&Bs[buf][rb * BK],                                         \
                  Bg + (size_t)(rb + srow) * KD + (t) * BK + scol);          \
    }                                                                        \
  }

  f32x4 ar[8];
  // prologue: tiles 0 and 1 fully staged (A via regs, B via DMA)
  ALOAD(ar, 0); AWRITE(ar, 0); BLOAD(0, 0);
  ALOAD(ar, 1); AWRITE(ar, 1); BLOAD(1, 1);

#pragma unroll
  for (int t = 0; t < NT; ++t) {
    int buf = t & 1;
    // B(t) DMA visible; only B(t+1)'s 2 loads stay in flight (A drained by
    // its AWRITE each iteration).
    if (t < NT - 1) {
      asm volatile("s_waitcnt vmcnt(2)" ::: "memory");
    } else {
      asm volatile("s_waitcnt vmcnt(0)" ::: "memory");
    }
    asm volatile("s_waitcnt lgkmcnt(0)" ::: "memory");
    SB0;
    __builtin_amdgcn_s_barrier();   // tile t visible to all 4 waves
    SB0;                            // pin: nothing hoists above the barrier

    // T14 issue-early: A(t+2) loads launched BEFORE the MFMA cluster
    if (t + 2 < NT) ALOAD(ar, t + 2);
    SB0;                            // pin issue point

    bf16x8 af[8], bfr[4];
#pragma unroll
    for (int ni = 0; ni < 4; ++ni)
      bfr[ni] = *(const bf16x8*)&Bs[buf][boff + ni * 16 * BK];
#pragma unroll
    for (int mi = 0; mi < 8; ++mi)
      af[mi] = *(const bf16x8*)&As[buf][aoff + mi * 16 * BK];
    __builtin_amdgcn_s_setprio(1);
#pragma unroll
    for (int mi = 0; mi < 8; ++mi)
#pragma unroll
      for (int ni = 0; ni < 4; ++ni)
        acc[mi][ni] = __builtin_amdgcn_mfma_f32_16x16x32_bf16(
            bfr[ni], af[mi], acc[mi][ni], 0, 0, 0);   // swapped (R15-proven)
    __builtin_amdgcn_s_setprio(0);

    // drain this tile's ds_reads before restaging over buf
    asm volatile("s_waitcnt lgkmcnt(0)" ::: "memory");
    SB0;
    __builtin_amdgcn_s_barrier();
    SB0;                            // pin: AWRITE/BLOAD cannot hoist above
    if (t + 2 < NT) {
      BLOAD(buf, t + 2);     // DMA first (stays in flight across iters)
      AWRITE(ar, buf);       // regs landed during MFMA; cvt+write ~free
    }
  }
#undef ALOAD
#undef AWRITE
#undef BLOAD

  // ---- write-coalesced epilogue: b128 staging + 512B-line nt stores ----
  size_t obase = (size_t)e * M_TOT * ND;
  int row0 = mt * BM;
  int col0 = nt * BN;
  float* Lh = Lep + (size_t)wm * (32 * 132);
#pragma unroll
  for (int r = 0; r < 4; ++r) {
#pragma unroll
    for (int m2 = 0; m2 < 2; ++m2) {
      int mi = 2 * r + m2;
#pragma unroll
      for (int ni = 0; ni < 4; ++ni)
        *(f32x4*)&Lh[(m2 * 16 + lr) * 132 + wn * 64 + ni * 16 + lk * 4] =
            acc[mi][ni];
    }
    asm volatile("s_waitcnt lgkmcnt(0)" ::: "memory");
    SB0;
    __builtin_amdgcn_s_barrier();
    SB0;
#pragma unroll
    for (int j = 0; j < 8; ++j) {
      int lrow = wn * 16 + j * 2 + (lane >> 5);
      int lc4 = lane & 31;
      f32x4 v = *(const f32x4*)&Lh[lrow * 132 + lc4 * 4];
      int grow = row0 + wm * 128 + r * 32 + lrow;
      __builtin_nontemporal_store(
          v, (f32x4*)&out[obase + (size_t)grow * ND + col0 + lc4 * 4]);
    }
    asm volatile("s_waitcnt lgkmcnt(0)" ::: "memory");
    SB0;
    __builtin_amdgcn_s_barrier();
    SB0;
  }
#undef SB0
}

extern "C" void kernel_launch(void* const* d_in, const int* in_sizes, int n_in,
                              void* d_out, int out_size, void* d_ws, size_t ws_size,
                              hipStream_t stream) {
  const float* x = (const float*)d_in[0];        // [B][S][D] f32
  const float* theta = (const float*)d_in[1];    // [E][R] f32
  const float* proj_w = (const float*)d_in[2];   // [E][D][D] f32
  float* out = (float*)d_out;                    // [E][B][S][D] f32

  __hip_bfloat16* Wb = (__hip_bfloat16*)d_ws;    // 4 MB

  hipLaunchKernelGGL(prep_w, dim3(ROT_B + WT_B), dim3(256), 0,
                     stream, theta, proj_w, Wb);
  // grid: (M_TOT/256)=64 mt  x  8 e  x  (512/128)=4 nt  = 2048 blocks
  hipLaunchKernelGGL(gemm_xw, dim3(2048), dim3(256), 0, stream, x, Wb, out);
}

// Round 21
// 115.143 us; speedup vs baseline: 6.2901x; 6.2901x over previous
//
#include <hip/hip_runtime.h>
#include <hip/hip_bf16.h>

#define E_ 8
#define B_ 8
#define S_ 2048
#define D_ 512
#define R_ 128
#define M_TOT (B_ * S_)   // 16384

typedef __attribute__((ext_vector_type(8))) short bf16x8;
typedef __attribute__((ext_vector_type(4))) float f32x4;
typedef __attribute__((ext_vector_type(4))) short s16x4;

__device__ __forceinline__ void gload_lds16(void* lds, const void* g) {
  __builtin_amdgcn_global_load_lds(
      (const __attribute__((address_space(1))) void*)g,
      (__attribute__((address_space(3))) void*)lds, 16, 0, 0);
}

// ---------------------------------------------------------------------------
// Prep kernel: W only (x conversion folded into the GEMM's A-staging).
//   [0,32)      rotation: W[e] cols 0..128 (one-shot slab, R13-proven)
//   [32,2080)   W tail cols 129..511 = bf16(proj_w)
// ---------------------------------------------------------------------------
#define ROT_B 32
#define WT_B 2048
__global__ __launch_bounds__(256) void prep_w(
    const float* __restrict__ theta, const float* __restrict__ pw,
    __hip_bfloat16* __restrict__ Wb) {
  int blk = blockIdx.x;
  int t = threadIdx.x;
  if (blk < ROT_B) {
    __shared__ float cs[R_], ss[R_];
    __shared__ float Pch[128][130];
    __shared__ __hip_bfloat16 Wch[128][130];
    int e = blk >> 2;
    int r0 = (blk & 3) * 128;
    if (t < R_) {
      float a = tanhf(theta[e * R_ + t]) * 0.1f;
      cs[t] = cosf(a);
      ss[t] = sinf(a);
    }
    const float* Pe = pw + (size_t)e * D_ * D_;
    __hip_bfloat16* We = Wb + (size_t)e * D_ * D_;
#pragma unroll 8
    for (int it = 0; it < 64; ++it) {
      int row = it * 2 + (t >> 7);
      int col = t & 127;
      Pch[row][col] = Pe[(size_t)(r0 + row) * D_ + col];
    }
    if (t < 128) Pch[t][128] = Pe[(size_t)(r0 + t) * D_ + 128];
    __syncthreads();
    if (t < 128) {
      float u = Pch[t][0];
#pragma unroll 16
      for (int k = 0; k < R_; ++k) {
        float pj = Pch[t][k + 1];
        Wch[t][k + 1] = __float2bfloat16(cs[k] * pj - ss[k] * u);
        u = cs[k] * u + ss[k] * pj;
      }
      Wch[t][0] = __float2bfloat16(u);
    }
    __syncthreads();
#pragma unroll 8
    for (int it = 0; it < 64; ++it) {
      int row = it * 2 + (t >> 7);
      int col = t & 127;
      We[(size_t)(r0 + row) * D_ + col] = Wch[row][col];
    }
    if (t < 128) We[(size_t)(r0 + t) * D_ + 128] = Wch[t][128];
  } else {
    int g = (blk - ROT_B) * 256 + t;
    int gidx = g & 127;
    if (gidx < 32) return;
    float4 v = ((const float4*)pw)[g];
    union { short4 s; __hip_bfloat16 h[4]; } u;
    u.h[0] = __float2bfloat16(v.x);
    u.h[1] = __float2bfloat16(v.y);
    u.h[2] = __float2bfloat16(v.z);
    u.h[3] = __float2bfloat16(v.w);
    if (gidx > 32) {
      ((short4*)Wb)[g] = u.s;
    } else {
      Wb[(size_t)g * 4 + 1] = u.h[1];
      Wb[(size_t)g * 4 + 2] = u.h[2];
      Wb[(size_t)g * 4 + 3] = u.h[3];
    }
  }
}

// ---------------------------------------------------------------------------
// GEMM: out[e] = x @ Wb[e]^T, A read directly as f32 (cached) + cvt in-kernel.
// R20's 724us root-caused: launch_bounds(256,3) capped VGPR at 84 -> acc
// spilled to scratch (FETCH 1.2GB, WRITE 2.4GB). R21: back to (256,2)
// (VGPR 124, no spill — R19-proven), keeping R20's cached A-loads (R19's
// FETCH=174MB proved nt-on-A defeats the XCD swizzle's L2 reuse).
// Schedule per iter t (race-fenced per rule #18: SB0 after every barrier):
//   [vmcnt(2); lgkm; SB0; s_barrier; SB0;
//    issue A(t+2) loads; SB0; MFMA(t);
//    lgkm; SB0; s_barrier; SB0; BLOAD(t+2); AWRITE(t+2)]
// ---------------------------------------------------------------------------
__global__ __launch_bounds__(256, 2) void gemm_xw(
    const float* __restrict__ Xf,            // [M_TOT][512] f32
    const __hip_bfloat16* __restrict__ Wb,   // [E][512][512] rows=o, cols=d
    float* __restrict__ out)                 // [E][M_TOT][512]
{
  constexpr int BM = 256, BN = 128, BK = 32;
  constexpr int KD = D_, ND = D_;
  constexpr int NT = KD / BK;  // 16
  __shared__ __align__(16) char smem[49152];
  __hip_bfloat16 (*As)[BM * BK] =
      (__hip_bfloat16 (*)[BM * BK]) & smem[0];         // 2 x 16 KB
  __hip_bfloat16 (*Bs)[BN * BK] =
      (__hip_bfloat16 (*)[BN * BK]) & smem[32768];     // 2 x 8 KB
  float* Lep = (float*)&smem[0];                       // epilogue: 2x32x132 f32

  int bx = blockIdx.x;            // 2048 blocks
  int xcd = bx & 7, c = bx >> 3;  // chunk c in [0,256) per XCD
  int e = c >> 5;                 // 0..7  (e-major within XCD)
  int msub = (c >> 2) & 7;        // 0..7
  int nt = c & 3;                 // 0..3
  int mt = xcd * 8 + msub;        // 0..63

  int tid = threadIdx.x;
  int wave = tid >> 6, lane = tid & 63;
  int lr = lane & 15, lk = lane >> 4;
  int wm = wave >> 1, wn = wave & 1;   // 2x2 waves; wave-tile 128x64

  const float* Ag = Xf + (size_t)(mt * BM) * KD;
  const __hip_bfloat16* Bg = Wb + ((size_t)e * ND + (size_t)nt * BN) * KD;

  int srow = lane >> 2;
  int scol = (lane & 3) * 8;
  int arow = lane >> 3;        // A: 8 rows per instr
  int acol = (lane & 7) * 4;   // f32 elems within row

  int aoff = (wm * 128 + lr) * BK + lk * 8;
  int boff = (wn * 64 + lr) * BK + lk * 8;

  f32x4 acc[8][4];
#pragma unroll
  for (int i = 0; i < 8; ++i)
#pragma unroll
    for (int j = 0; j < 4; ++j) acc[i][j] = (f32x4){0.f, 0.f, 0.f, 0.f};

#define SB0 __builtin_amdgcn_sched_barrier(0)

#define ALOAD(ar, t)                                                         \
  {                                                                          \
    _Pragma("unroll") for (int j = 0; j < 8; ++j) {                          \
      int row = wave * 64 + j * 8 + arow;                                    \
      ar[j] = *(const f32x4*)(Ag + (size_t)row * KD + (t) * BK + acol);      \
    }                                                                        \
  }
#define AWRITE(ar, buf)                                                      \
  {                                                                          \
    _Pragma("unroll") for (int j = 0; j < 8; ++j) {                          \
      int row = wave * 64 + j * 8 + arow;                                    \
      union { s16x4 s; __hip_bfloat16 h[4]; } u;                             \
      u.h[0] = __float2bfloat16(ar[j].x);                                    \
      u.h[1] = __float2bfloat16(ar[j].y);                                    \
      u.h[2] = __float2bfloat16(ar[j].z);                                    \
      u.h[3] = __float2bfloat16(ar[j].w);                                    \
      *(s16x4*)&As[buf][row * BK + acol] = u.s;                              \
    }                                                                        \
  }
#define BLOAD(buf, t)                                                        \
  {                                                                          \
    _Pragma("unroll") for (int g = 0; g < 2; ++g) {                          \
      int rb = wave * 32 + g * 16;                                           \
      gload_lds16(&Bs[buf][rb * BK],                                         \
                  Bg + (size_t)(rb + srow) * KD + (t) * BK + scol);          \
    }                                                                        \
  }

  f32x4 ar[8];
  // prologue: tiles 0 and 1 fully staged (A via regs, B via DMA)
  ALOAD(ar, 0); AWRITE(ar, 0); BLOAD(0, 0);
  ALOAD(ar, 1); AWRITE(ar, 1); BLOAD(1, 1);

#pragma unroll
  for (int t = 0; t < NT; ++t) {
    int buf = t & 1;
    // B(t) DMA visible; only B(t+1)'s 2 loads stay in flight (A drained by
    // its AWRITE each iteration).
    if (t < NT - 1) {
      asm volatile("s_waitcnt vmcnt(2)" ::: "memory");
    } else {
      asm volatile("s_waitcnt vmcnt(0)" ::: "memory");
    }
    asm volatile("s_waitcnt lgkmcnt(0)" ::: "memory");
    SB0;
    __builtin_amdgcn_s_barrier();   // tile t visible to all 4 waves
    SB0;                            // pin: nothing hoists above the barrier

    // T14 issue-early: A(t+2) loads launched BEFORE the MFMA cluster
    if (t + 2 < NT) ALOAD(ar, t + 2);
    SB0;                            // pin issue point

    bf16x8 af[8], bfr[4];
#pragma unroll
    for (int ni = 0; ni < 4; ++ni)
      bfr[ni] = *(const bf16x8*)&Bs[buf][boff + ni * 16 * BK];
#pragma unroll
    for (int mi = 0; mi < 8; ++mi)
      af[mi] = *(const bf16x8*)&As[buf][aoff + mi * 16 * BK];
    __builtin_amdgcn_s_setprio(1);
#pragma unroll
    for (int mi = 0; mi < 8; ++mi)
#pragma unroll
      for (int ni = 0; ni < 4; ++ni)
        acc[mi][ni] = __builtin_amdgcn_mfma_f32_16x16x32_bf16(
            bfr[ni], af[mi], acc[mi][ni], 0, 0, 0);   // swapped (R15-proven)
    __builtin_amdgcn_s_setprio(0);

    // drain this tile's ds_reads before restaging over buf
    asm volatile("s_waitcnt lgkmcnt(0)" ::: "memory");
    SB0;
    __builtin_amdgcn_s_barrier();
    SB0;                            // pin: AWRITE/BLOAD cannot hoist above
    if (t + 2 < NT) {
      BLOAD(buf, t + 2);     // DMA first (stays in flight across iters)
      AWRITE(ar, buf);       // regs landed during MFMA; cvt+write ~free
    }
  }
#undef ALOAD
#undef AWRITE
#undef BLOAD

  // ---- write-coalesced epilogue: b128 staging + 512B-line nt stores ----
  size_t obase = (size_t)e * M_TOT * ND;
  int row0 = mt * BM;
  int col0 = nt * BN;
  float* Lh = Lep + (size_t)wm * (32 * 132);
#pragma unroll
  for (int r = 0; r < 4; ++r) {
#pragma unroll
    for (int m2 = 0; m2 < 2; ++m2) {
      int mi = 2 * r + m2;
#pragma unroll
      for (int ni = 0; ni < 4; ++ni)
        *(f32x4*)&Lh[(m2 * 16 + lr) * 132 + wn * 64 + ni * 16 + lk * 4] =
            acc[mi][ni];
    }
    asm volatile("s_waitcnt lgkmcnt(0)" ::: "memory");
    SB0;
    __builtin_amdgcn_s_barrier();
    SB0;
#pragma unroll
    for (int j = 0; j < 8; ++j) {
      int lrow = wn * 16 + j * 2 + (lane >> 5);
      int lc4 = lane & 31;
      f32x4 v = *(const f32x4*)&Lh[lrow * 132 + lc4 * 4];
      int grow = row0 + wm * 128 + r * 32 + lrow;
      __builtin_nontemporal_store(
          v, (f32x4*)&out[obase + (size_t)grow * ND + col0 + lc4 * 4]);
    }
    asm volatile("s_waitcnt lgkmcnt(0)" ::: "memory");
    SB0;
    __builtin_amdgcn_s_barrier();
    SB0;
  }
#undef SB0
}

extern "C" void kernel_launch(void* const* d_in, const int* in_sizes, int n_in,
                              void* d_out, int out_size, void* d_ws, size_t ws_size,
                              hipStream_t stream) {
  const float* x = (const float*)d_in[0];        // [B][S][D] f32
  const float* theta = (const float*)d_in[1];    // [E][R] f32
  const float* proj_w = (const float*)d_in[2];   // [E][D][D] f32
  float* out = (float*)d_out;                    // [E][B][S][D] f32

  __hip_bfloat16* Wb = (__hip_bfloat16*)d_ws;    // 4 MB

  hipLaunchKernelGGL(prep_w, dim3(ROT_B + WT_B), dim3(256), 0,
                     stream, theta, proj_w, Wb);
  // grid: (M_TOT/256)=64 mt  x  8 e  x  (512/128)=4 nt  = 2048 blocks
  hipLaunchKernelGGL(gemm_xw, dim3(2048), dim3(256), 0, stream, x, Wb, out);
}

// Round 22
// 105.034 us; speedup vs baseline: 6.8955x; 1.0962x over previous
//
#include <hip/hip_runtime.h>
#include <hip/hip_bf16.h>

#define E_ 8
#define B_ 8
#define S_ 2048
#define D_ 512
#define R_ 128
#define M_TOT (B_ * S_)   // 16384

typedef __attribute__((ext_vector_type(8))) short bf16x8;
typedef __attribute__((ext_vector_type(4))) float f32x4;
typedef __attribute__((ext_vector_type(4))) short s16x4;

__device__ __forceinline__ void gload_lds16(void* lds, const void* g) {
  __builtin_amdgcn_global_load_lds(
      (const __attribute__((address_space(1))) void*)g,
      (__attribute__((address_space(3))) void*)lds, 16, 0, 0);
}

// ---------------------------------------------------------------------------
// Fused prep kernel (R13/R16-proven): rot one-shot slab | W tail | x -> bf16.
// W-tail pw reads now nontemporal (read-once, disjoint from rot's cols).
// ---------------------------------------------------------------------------
#define ROT_B 32
#define WT_B 2048
#define CX_B 4096
__global__ __launch_bounds__(256) void prep_fused(
    const float* __restrict__ x, const float* __restrict__ theta,
    const float* __restrict__ pw, __hip_bfloat16* __restrict__ xb,
    __hip_bfloat16* __restrict__ Wb) {
  int blk = blockIdx.x;
  int t = threadIdx.x;
  if (blk < ROT_B) {
    __shared__ float cs[R_], ss[R_];
    __shared__ float Pch[128][130];
    __shared__ __hip_bfloat16 Wch[128][130];
    int e = blk >> 2;
    int r0 = (blk & 3) * 128;
    if (t < R_) {
      float a = tanhf(theta[e * R_ + t]) * 0.1f;
      cs[t] = cosf(a);
      ss[t] = sinf(a);
    }
    const float* Pe = pw + (size_t)e * D_ * D_;
    __hip_bfloat16* We = Wb + (size_t)e * D_ * D_;
#pragma unroll 8
    for (int it = 0; it < 64; ++it) {
      int row = it * 2 + (t >> 7);
      int col = t & 127;
      Pch[row][col] = Pe[(size_t)(r0 + row) * D_ + col];
    }
    if (t < 128) Pch[t][128] = Pe[(size_t)(r0 + t) * D_ + 128];
    __syncthreads();
    if (t < 128) {
      float u = Pch[t][0];
#pragma unroll 16
      for (int k = 0; k < R_; ++k) {
        float pj = Pch[t][k + 1];
        Wch[t][k + 1] = __float2bfloat16(cs[k] * pj - ss[k] * u);
        u = cs[k] * u + ss[k] * pj;
      }
      Wch[t][0] = __float2bfloat16(u);
    }
    __syncthreads();
#pragma unroll 8
    for (int it = 0; it < 64; ++it) {
      int row = it * 2 + (t >> 7);
      int col = t & 127;
      We[(size_t)(r0 + row) * D_ + col] = Wch[row][col];
    }
    if (t < 128) We[(size_t)(r0 + t) * D_ + 128] = Wch[t][128];
  } else if (blk < ROT_B + WT_B) {
    int g = (blk - ROT_B) * 256 + t;
    int gidx = g & 127;
    if (gidx < 32) return;
    f32x4 v = __builtin_nontemporal_load(&((const f32x4*)pw)[g]);
    union { s16x4 s; __hip_bfloat16 h[4]; } u;
    u.h[0] = __float2bfloat16(v.x);
    u.h[1] = __float2bfloat16(v.y);
    u.h[2] = __float2bfloat16(v.z);
    u.h[3] = __float2bfloat16(v.w);
    if (gidx > 32) {
      ((s16x4*)Wb)[g] = u.s;
    } else {
      Wb[(size_t)g * 4 + 1] = u.h[1];
      Wb[(size_t)g * 4 + 2] = u.h[2];
      Wb[(size_t)g * 4 + 3] = u.h[3];
    }
  } else {
    int i = (blk - ROT_B - WT_B) * 256 + t;
#pragma unroll
    for (int rep = 0; rep < 2; ++rep) {
      int idx = i + rep * (CX_B * 256);
      f32x4 v = __builtin_nontemporal_load(&((const f32x4*)x)[idx]);
      union { s16x4 s; __hip_bfloat16 h[4]; } u;
      u.h[0] = __float2bfloat16(v.x);
      u.h[1] = __float2bfloat16(v.y);
      u.h[2] = __float2bfloat16(v.z);
      u.h[3] = __float2bfloat16(v.w);
      ((s16x4*)xb)[idx] = u.s;
    }
  }
}

// ---------------------------------------------------------------------------
// GEMM (R16, best-known 103.7us): out[e] = Xb @ Wb[e]^T (NT).
// 256x128 block, 4 waves, BK=32 dbuf, counted vmcnt(6), 2 blocks/CU,
// XCD e-major swizzle, swapped-operand MFMA (lane's acc = contiguous 16B of
// an out row), b128-staged full-line epilogue with nontemporal stores.
// ---------------------------------------------------------------------------
__global__ __launch_bounds__(256, 2) void gemm_xw(
    const __hip_bfloat16* __restrict__ Xb,   // [M_TOT][512]
    const __hip_bfloat16* __restrict__ Wb,   // [E][512][512] rows=o, cols=d
    float* __restrict__ out)                 // [E][M_TOT][512]
{
  constexpr int BM = 256, BN = 128, BK = 32;
  constexpr int KD = D_, ND = D_;
  constexpr int NT = KD / BK;  // 16
  __shared__ __align__(16) char smem[49152];
  __hip_bfloat16 (*As)[BM * BK] =
      (__hip_bfloat16 (*)[BM * BK]) & smem[0];         // 2 x 16 KB
  __hip_bfloat16 (*Bs)[BN * BK] =
      (__hip_bfloat16 (*)[BN * BK]) & smem[32768];     // 2 x 8 KB
  float* Lep = (float*)&smem[0];                       // epilogue: 2x32x132 f32

  int bx = blockIdx.x;            // 2048 blocks
  int xcd = bx & 7, c = bx >> 3;  // chunk c in [0,256) per XCD
  int e = c >> 5;                 // 0..7  (e-major within XCD)
  int msub = (c >> 2) & 7;        // 0..7
  int nt = c & 3;                 // 0..3
  int mt = xcd * 8 + msub;        // 0..63

  int tid = threadIdx.x;
  int wave = tid >> 6, lane = tid & 63;
  int lr = lane & 15, lk = lane >> 4;
  int wm = wave >> 1, wn = wave & 1;   // 2x2 waves; wave-tile 128x64

  const __hip_bfloat16* Ag = Xb + (size_t)(mt * BM) * KD;
  const __hip_bfloat16* Bg = Wb + ((size_t)e * ND + (size_t)nt * BN) * KD;

  int srow = lane >> 2;
  int scol = (lane & 3) * 8;

  int aoff = (wm * 128 + lr) * BK + lk * 8;
  int boff = (wn * 64 + lr) * BK + lk * 8;

  f32x4 acc[8][4];
#pragma unroll
  for (int i = 0; i < 8; ++i)
#pragma unroll
    for (int j = 0; j < 4; ++j) acc[i][j] = (f32x4){0.f, 0.f, 0.f, 0.f};

#define STAGE(buf, t)                                                        \
  {                                                                          \
    _Pragma("unroll") for (int g = 0; g < 4; ++g) {                          \
      int rb = wave * 64 + g * 16;                                           \
      gload_lds16(&As[buf][rb * BK],                                         \
                  Ag + (size_t)(rb + srow) * KD + (t) * BK + scol);          \
    }                                                                        \
    _Pragma("unroll") for (int g = 0; g < 2; ++g) {                          \
      int rb = wave * 32 + g * 16;                                           \
      gload_lds16(&Bs[buf][rb * BK],                                         \
                  Bg + (size_t)(rb + srow) * KD + (t) * BK + scol);          \
    }                                                                        \
  }

  STAGE(0, 0);
  STAGE(1, 1);

#pragma unroll
  for (int t = 0; t < NT; ++t) {
    int buf = t & 1;
    if (t < NT - 1) {
      asm volatile("s_waitcnt vmcnt(6)" ::: "memory");
    } else {
      asm volatile("s_waitcnt vmcnt(0)" ::: "memory");
    }
    __builtin_amdgcn_s_barrier();   // tile t visible to all 4 waves

    bf16x8 af[8], bfr[4];
#pragma unroll
    for (int ni = 0; ni < 4; ++ni)
      bfr[ni] = *(const bf16x8*)&Bs[buf][boff + ni * 16 * BK];
#pragma unroll
    for (int mi = 0; mi < 8; ++mi)
      af[mi] = *(const bf16x8*)&As[buf][aoff + mi * 16 * BK];
    __builtin_amdgcn_s_setprio(1);
#pragma unroll
    for (int mi = 0; mi < 8; ++mi)
#pragma unroll
      for (int ni = 0; ni < 4; ++ni)
        acc[mi][ni] = __builtin_amdgcn_mfma_f32_16x16x32_bf16(
            bfr[ni], af[mi], acc[mi][ni], 0, 0, 0);   // swapped (R15-proven)
    __builtin_amdgcn_s_setprio(0);

    asm volatile("s_waitcnt lgkmcnt(0)" ::: "memory");
    __builtin_amdgcn_sched_barrier(0);
    __builtin_amdgcn_s_barrier();
    if (t + 2 < NT) STAGE(buf, t + 2);
  }
#undef STAGE

  // ---- write-coalesced epilogue: b128 staging + 512B-line nt stores ----
  size_t obase = (size_t)e * M_TOT * ND;
  int row0 = mt * BM;
  int col0 = nt * BN;
  float* Lh = Lep + (size_t)wm * (32 * 132);
#pragma unroll
  for (int r = 0; r < 4; ++r) {
#pragma unroll
    for (int m2 = 0; m2 < 2; ++m2) {
      int mi = 2 * r + m2;
#pragma unroll
      for (int ni = 0; ni < 4; ++ni)
        *(f32x4*)&Lh[(m2 * 16 + lr) * 132 + wn * 64 + ni * 16 + lk * 4] =
            acc[mi][ni];
    }
    __builtin_amdgcn_s_barrier();
#pragma unroll
    for (int j = 0; j < 8; ++j) {
      int lrow = wn * 16 + j * 2 + (lane >> 5);
      int lc4 = lane & 31;
      f32x4 v = *(const f32x4*)&Lh[lrow * 132 + lc4 * 4];
      int grow = row0 + wm * 128 + r * 32 + lrow;
      __builtin_nontemporal_store(
          v, (f32x4*)&out[obase + (size_t)grow * ND + col0 + lc4 * 4]);
    }
    __builtin_amdgcn_s_barrier();
  }
}

extern "C" void kernel_launch(void* const* d_in, const int* in_sizes, int n_in,
                              void* d_out, int out_size, void* d_ws, size_t ws_size,
                              hipStream_t stream) {
  const float* x = (const float*)d_in[0];        // [B][S][D] f32
  const float* theta = (const float*)d_in[1];    // [E][R] f32
  const float* proj_w = (const float*)d_in[2];   // [E][D][D] f32
  float* out = (float*)d_out;                    // [E][B][S][D] f32

  __hip_bfloat16* xb = (__hip_bfloat16*)d_ws;                          // 16 MB
  __hip_bfloat16* Wb = (__hip_bfloat16*)((char*)d_ws +
                        (size_t)M_TOT * D_ * sizeof(__hip_bfloat16));  // 4 MB

  hipLaunchKernelGGL(prep_fused, dim3(ROT_B + WT_B + CX_B), dim3(256), 0,
                     stream, x, theta, proj_w, xb, Wb);
  // grid: (M_TOT/256)=64 mt  x  8 e  x  (512/128)=4 nt  = 2048 blocks
  hipLaunchKernelGGL(gemm_xw, dim3(2048), dim3(256), 0, stream, xb, Wb, out);
}

// Round 24
// 103.882 us; speedup vs baseline: 6.9719x; 1.0111x over previous
//
#include <hip/hip_runtime.h>
#include <hip/hip_bf16.h>

#define E_ 8
#define B_ 8
#define S_ 2048
#define D_ 512
#define R_ 128
#define M_TOT (B_ * S_)   // 16384

typedef __attribute__((ext_vector_type(8))) short bf16x8;
typedef __attribute__((ext_vector_type(4))) float f32x4;
typedef __attribute__((ext_vector_type(4))) short s16x4;

__device__ __forceinline__ void gload_lds16(void* lds, const void* g) {
  __builtin_amdgcn_global_load_lds(
      (const __attribute__((address_space(1))) void*)g,
      (__attribute__((address_space(3))) void*)lds, 16, 0, 0);
}

// ---------------------------------------------------------------------------
// Fused prep kernel (R13-proven): rot one-shot slab | W tail | x -> bf16 (nt)
// ---------------------------------------------------------------------------
#define ROT_B 32
#define WT_B 2048
#define CX_B 4096
__global__ __launch_bounds__(256) void prep_fused(
    const float* __restrict__ x, const float* __restrict__ theta,
    const float* __restrict__ pw, __hip_bfloat16* __restrict__ xb,
    __hip_bfloat16* __restrict__ Wb) {
  int blk = blockIdx.x;
  int t = threadIdx.x;
  if (blk < ROT_B) {
    __shared__ float cs[R_], ss[R_];
    __shared__ float Pch[128][130];
    __shared__ __hip_bfloat16 Wch[128][130];
    int e = blk >> 2;
    int r0 = (blk & 3) * 128;
    if (t < R_) {
      float a = tanhf(theta[e * R_ + t]) * 0.1f;
      cs[t] = cosf(a);
      ss[t] = sinf(a);
    }
    const float* Pe = pw + (size_t)e * D_ * D_;
    __hip_bfloat16* We = Wb + (size_t)e * D_ * D_;
#pragma unroll 8
    for (int it = 0; it < 64; ++it) {
      int row = it * 2 + (t >> 7);
      int col = t & 127;
      Pch[row][col] = Pe[(size_t)(r0 + row) * D_ + col];
    }
    if (t < 128) Pch[t][128] = Pe[(size_t)(r0 + t) * D_ + 128];
    __syncthreads();
    if (t < 128) {
      float u = Pch[t][0];
#pragma unroll 16
      for (int k = 0; k < R_; ++k) {
        float pj = Pch[t][k + 1];
        Wch[t][k + 1] = __float2bfloat16(cs[k] * pj - ss[k] * u);
        u = cs[k] * u + ss[k] * pj;
      }
      Wch[t][0] = __float2bfloat16(u);
    }
    __syncthreads();
#pragma unroll 8
    for (int it = 0; it < 64; ++it) {
      int row = it * 2 + (t >> 7);
      int col = t & 127;
      We[(size_t)(r0 + row) * D_ + col] = Wch[row][col];
    }
    if (t < 128) We[(size_t)(r0 + t) * D_ + 128] = Wch[t][128];
  } else if (blk < ROT_B + WT_B) {
    int g = (blk - ROT_B) * 256 + t;
    int gidx = g & 127;
    if (gidx < 32) return;
    float4 v = ((const float4*)pw)[g];
    union { short4 s; __hip_bfloat16 h[4]; } u;
    u.h[0] = __float2bfloat16(v.x);
    u.h[1] = __float2bfloat16(v.y);
    u.h[2] = __float2bfloat16(v.z);
    u.h[3] = __float2bfloat16(v.w);
    if (gidx > 32) {
      ((short4*)Wb)[g] = u.s;
    } else {
      Wb[(size_t)g * 4 + 1] = u.h[1];
      Wb[(size_t)g * 4 + 2] = u.h[2];
      Wb[(size_t)g * 4 + 3] = u.h[3];
    }
  } else {
    int i = (blk - ROT_B - WT_B) * 256 + t;
#pragma unroll
    for (int rep = 0; rep < 2; ++rep) {
      int idx = i + rep * (CX_B * 256);
      f32x4 v = __builtin_nontemporal_load(&((const f32x4*)x)[idx]);
      union { s16x4 s; __hip_bfloat16 h[4]; } u;
      u.h[0] = __float2bfloat16(v.x);
      u.h[1] = __float2bfloat16(v.y);
      u.h[2] = __float2bfloat16(v.z);
      u.h[3] = __float2bfloat16(v.w);
      ((s16x4*)xb)[idx] = u.s;
    }
  }
}

// ---------------------------------------------------------------------------
// GEMM (R16, best-known 103.7us): out[e] = Xb @ Wb[e]^T (NT).
// 256x128 block, 4 waves, BK=32 dbuf, counted vmcnt(6), 2 blocks/CU,
// XCD e-major swizzle, swapped-operand MFMA (lane's acc = contiguous 16B of
// an out row), b128-staged full-line epilogue with nontemporal stores.
// ---------------------------------------------------------------------------
__global__ __launch_bounds__(256, 2) void gemm_xw(
    const __hip_bfloat16* __restrict__ Xb,   // [M_TOT][512]
    const __hip_bfloat16* __restrict__ Wb,   // [E][512][512] rows=o, cols=d
    float* __restrict__ out)                 // [E][M_TOT][512]
{
  constexpr int BM = 256, BN = 128, BK = 32;
  constexpr int KD = D_, ND = D_;
  constexpr int NT = KD / BK;  // 16
  __shared__ __align__(16) char smem[49152];
  __hip_bfloat16 (*As)[BM * BK] =
      (__hip_bfloat16 (*)[BM * BK]) & smem[0];         // 2 x 16 KB
  __hip_bfloat16 (*Bs)[BN * BK] =
      (__hip_bfloat16 (*)[BN * BK]) & smem[32768];     // 2 x 8 KB
  float* Lep = (float*)&smem[0];                       // epilogue: 2x32x132 f32

  int bx = blockIdx.x;            // 2048 blocks
  int xcd = bx & 7, c = bx >> 3;  // chunk c in [0,256) per XCD
  int e = c >> 5;                 // 0..7  (e-major within XCD)
  int msub = (c >> 2) & 7;        // 0..7
  int nt = c & 3;                 // 0..3
  int mt = xcd * 8 + msub;        // 0..63

  int tid = threadIdx.x;
  int wave = tid >> 6, lane = tid & 63;
  int lr = lane & 15, lk = lane >> 4;
  int wm = wave >> 1, wn = wave & 1;   // 2x2 waves; wave-tile 128x64

  const __hip_bfloat16* Ag = Xb + (size_t)(mt * BM) * KD;
  const __hip_bfloat16* Bg = Wb + ((size_t)e * ND + (size_t)nt * BN) * KD;

  int srow = lane >> 2;
  int scol = (lane & 3) * 8;

  int aoff = (wm * 128 + lr) * BK + lk * 8;
  int boff = (wn * 64 + lr) * BK + lk * 8;

  f32x4 acc[8][4];
#pragma unroll
  for (int i = 0; i < 8; ++i)
#pragma unroll
    for (int j = 0; j < 4; ++j) acc[i][j] = (f32x4){0.f, 0.f, 0.f, 0.f};

#define STAGE(buf, t)                                                        \
  {                                                                          \
    _Pragma("unroll") for (int g = 0; g < 4; ++g) {                          \
      int rb = wave * 64 + g * 16;                                           \
      gload_lds16(&As[buf][rb * BK],                                         \
                  Ag + (size_t)(rb + srow) * KD + (t) * BK + scol);          \
    }                                                                        \
    _Pragma("unroll") for (int g = 0; g < 2; ++g) {                          \
      int rb = wave * 32 + g * 16;                                           \
      gload_lds16(&Bs[buf][rb * BK],                                         \
                  Bg + (size_t)(rb + srow) * KD + (t) * BK + scol);          \
    }                                                                        \
  }

  STAGE(0, 0);
  STAGE(1, 1);

#pragma unroll
  for (int t = 0; t < NT; ++t) {
    int buf = t & 1;
    if (t < NT - 1) {
      asm volatile("s_waitcnt vmcnt(6)" ::: "memory");
    } else {
      asm volatile("s_waitcnt vmcnt(0)" ::: "memory");
    }
    __builtin_amdgcn_s_barrier();   // tile t visible to all 4 waves

    bf16x8 af[8], bfr[4];
#pragma unroll
    for (int ni = 0; ni < 4; ++ni)
      bfr[ni] = *(const bf16x8*)&Bs[buf][boff + ni * 16 * BK];
#pragma unroll
    for (int mi = 0; mi < 8; ++mi)
      af[mi] = *(const bf16x8*)&As[buf][aoff + mi * 16 * BK];
    __builtin_amdgcn_s_setprio(1);
#pragma unroll
    for (int mi = 0; mi < 8; ++mi)
#pragma unroll
      for (int ni = 0; ni < 4; ++ni)
        acc[mi][ni] = __builtin_amdgcn_mfma_f32_16x16x32_bf16(
            bfr[ni], af[mi], acc[mi][ni], 0, 0, 0);   // swapped (R15-proven)
    __builtin_amdgcn_s_setprio(0);

    asm volatile("s_waitcnt lgkmcnt(0)" ::: "memory");
    __builtin_amdgcn_sched_barrier(0);
    __builtin_amdgcn_s_barrier();
    if (t + 2 < NT) STAGE(buf, t + 2);
  }
#undef STAGE

  // ---- write-coalesced epilogue: b128 staging + 512B-line nt stores ----
  size_t obase = (size_t)e * M_TOT * ND;
  int row0 = mt * BM;
  int col0 = nt * BN;
  float* Lh = Lep + (size_t)wm * (32 * 132);
#pragma unroll
  for (int r = 0; r < 4; ++r) {
#pragma unroll
    for (int m2 = 0; m2 < 2; ++m2) {
      int mi = 2 * r + m2;
#pragma unroll
      for (int ni = 0; ni < 4; ++ni)
        *(f32x4*)&Lh[(m2 * 16 + lr) * 132 + wn * 64 + ni * 16 + lk * 4] =
            acc[mi][ni];
    }
    __builtin_amdgcn_s_barrier();
#pragma unroll
    for (int j = 0; j < 8; ++j) {
      int lrow = wn * 16 + j * 2 + (lane >> 5);
      int lc4 = lane & 31;
      f32x4 v = *(const f32x4*)&Lh[lrow * 132 + lc4 * 4];
      int grow = row0 + wm * 128 + r * 32 + lrow;
      __builtin_nontemporal_store(
          v, (f32x4*)&out[obase + (size_t)grow * ND + col0 + lc4 * 4]);
    }
    __builtin_amdgcn_s_barrier();
  }
}

extern "C" void kernel_launch(void* const* d_in, const int* in_sizes, int n_in,
                              void* d_out, int out_size, void* d_ws, size_t ws_size,
                              hipStream_t stream) {
  const float* x = (const float*)d_in[0];        // [B][S][D] f32
  const float* theta = (const float*)d_in[1];    // [E][R] f32
  const float* proj_w = (const float*)d_in[2];   // [E][D][D] f32
  float* out = (float*)d_out;                    // [E][B][S][D] f32

  __hip_bfloat16* xb = (__hip_bfloat16*)d_ws;                          // 16 MB
  __hip_bfloat16* Wb = (__hip_bfloat16*)((char*)d_ws +
                        (size_t)M_TOT * D_ * sizeof(__hip_bfloat16));  // 4 MB

  hipLaunchKernelGGL(prep_fused, dim3(ROT_B + WT_B + CX_B), dim3(256), 0,
                     stream, x, theta, proj_w, xb, Wb);
  // grid: (M_TOT/256)=64 mt  x  8 e  x  (512/128)=4 nt  = 2048 blocks
  hipLaunchKernelGGL(gemm_xw, dim3(2048), dim3(256), 0, stream, xb, Wb, out);
}